// Round 4
// baseline (8586.292 us; speedup 1.0000x reference)
//
#include <hip/hip_runtime.h>
#include <stdint.h>

// Problem dims (fixed by setup_inputs)
#define BB 8
#define SS 2048
#define DD 1024
#define HH 4096
#define MM 256

typedef short bf16x8 __attribute__((ext_vector_type(8)));   // 8 bf16 in 4 VGPRs
typedef float f32x4 __attribute__((ext_vector_type(4)));

__device__ inline unsigned short f2bf(float f){
  unsigned u = __builtin_bit_cast(unsigned, f);
  return (unsigned short)((u + 0x7FFFu + ((u >> 16) & 1u)) >> 16);  // RNE
}

// ---------------- pack f32 -> bf16 (4 elems/thread) ----------------
__global__ void ssma_pack_bf16(const float* __restrict__ src,
                               unsigned short* __restrict__ dst, int n4){
  int i = blockIdx.x * blockDim.x + threadIdx.x;
  if (i < n4){
    float4 v = ((const float4*)src)[i];
    ushort4 o;
    o.x = f2bf(v.x); o.y = f2bf(v.y); o.z = f2bf(v.z); o.w = f2bf(v.w);
    ((ushort4*)dst)[i] = o;
  }
}

// ---------------- bf16 MFMA GEMM, C = A * B^T (+epilogue) ----------------
template<int EPI>
__global__ __launch_bounds__(256) void ssma_gemm_bt(
    const unsigned short* __restrict__ A, const unsigned short* __restrict__ Bw,
    int K, int N, const float* __restrict__ bias,
    const float* __restrict__ resid, void* __restrict__ Cout)
{
  __shared__ uint4 As4[512];   // 128x32 bf16 = 8KB
  __shared__ uint4 Bs4[512];
  unsigned short* As = (unsigned short*)As4;
  unsigned short* Bs = (unsigned short*)Bs4;

  const int tid  = threadIdx.x;
  const int lane = tid & 63;
  const int wv   = tid >> 6;
  const int wm   = wv >> 1, wn = wv & 1;      // 2x2 wave grid, 64x64 per wave
  const int m0   = blockIdx.y * 128;
  const int n0   = blockIdx.x * 128;
  const int kq   = lane >> 4;
  const int rl   = lane & 15;

  f32x4 acc[4][4];
#pragma unroll
  for (int a = 0; a < 4; ++a)
#pragma unroll
    for (int b = 0; b < 4; ++b) acc[a][b] = (f32x4){0.f, 0.f, 0.f, 0.f};

  for (int k0 = 0; k0 < K; k0 += 32){
    __syncthreads();
#pragma unroll
    for (int i = 0; i < 2; ++i){
      int c  = tid + 256 * i;
      int r  = c >> 2;
      int c8 = (c & 3) * 8;
      As4[c] = *(const uint4*)(A  + (size_t)(m0 + r) * K + k0 + c8);
      Bs4[c] = *(const uint4*)(Bw + (size_t)(n0 + r) * K + k0 + c8);
    }
    __syncthreads();

    const bf16x8* Ap = (const bf16x8*)As;
    const bf16x8* Bp = (const bf16x8*)Bs;
    bf16x8 af[4], bfr[4];
#pragma unroll
    for (int mi = 0; mi < 4; ++mi) af[mi]  = Ap[(wm * 64 + mi * 16 + rl) * 4 + kq];
#pragma unroll
    for (int ni = 0; ni < 4; ++ni) bfr[ni] = Bp[(wn * 64 + ni * 16 + rl) * 4 + kq];
#pragma unroll
    for (int mi = 0; mi < 4; ++mi)
#pragma unroll
      for (int ni = 0; ni < 4; ++ni)
        acc[mi][ni] = __builtin_amdgcn_mfma_f32_16x16x32_bf16(af[mi], bfr[ni], acc[mi][ni], 0, 0, 0);
  }

#pragma unroll
  for (int mi = 0; mi < 4; ++mi){
#pragma unroll
    for (int ni = 0; ni < 4; ++ni){
      int col = n0 + wn * 64 + ni * 16 + rl;
      float bv = bias[col];
#pragma unroll
      for (int r = 0; r < 4; ++r){
        int row = m0 + wm * 64 + mi * 16 + kq * 4 + r;
        float v = acc[mi][ni][r] + bv;
        if (EPI == 0){
          v = fmaxf(v, 0.0f);
          ((unsigned short*)Cout)[(size_t)row * N + col] = f2bf(v);
        } else {
          v += resid[(size_t)row * N + col];
          ((float*)Cout)[(size_t)row * N + col] = v;
        }
      }
    }
  }
}

// ---------------- exact-f32 GEMM: xproj = x * win_w^T + win_b ----------------
__global__ __launch_bounds__(256) void ssma_gemm3_f32(
    const float* __restrict__ A, const float* __restrict__ Bw,
    const float* __restrict__ bias, float* __restrict__ C)
{
  __shared__ float As[64][17];
  __shared__ float Bs[64][17];
  const int tid = threadIdx.x;
  const int tx = tid & 15, ty = tid >> 4;
  const int m0 = blockIdx.y * 64, n0 = blockIdx.x * 64;
  float acc[4][4];
#pragma unroll
  for (int i = 0; i < 4; ++i)
#pragma unroll
    for (int j = 0; j < 4; ++j) acc[i][j] = 0.f;

  for (int k0 = 0; k0 < DD; k0 += 16){
    __syncthreads();
#pragma unroll
    for (int i = 0; i < 4; ++i){
      int e = tid + 256 * i;
      int r = e >> 4, c = e & 15;
      As[r][c] = A [(size_t)(m0 + r) * DD + k0 + c];
      Bs[r][c] = Bw[(size_t)(n0 + r) * DD + k0 + c];
    }
    __syncthreads();
#pragma unroll
    for (int kk = 0; kk < 16; ++kk){
      float a[4], b[4];
#pragma unroll
      for (int i = 0; i < 4; ++i) a[i] = As[ty * 4 + i][kk];
#pragma unroll
      for (int j = 0; j < 4; ++j) b[j] = Bs[tx * 4 + j][kk];
#pragma unroll
      for (int i = 0; i < 4; ++i)
#pragma unroll
        for (int j = 0; j < 4; ++j) acc[i][j] = fmaf(a[i], b[j], acc[i][j]);
    }
  }
#pragma unroll
  for (int i = 0; i < 4; ++i){
    int row = m0 + ty * 4 + i;
#pragma unroll
    for (int j = 0; j < 4; ++j){
      int col = n0 + tx * 4 + j;
      C[(size_t)row * MM + col] = acc[i][j] + bias[col];
    }
  }
}

// ---------------- 256x256 f32 transpose (wstate -> wT) ----------------
__global__ __launch_bounds__(256) void ssma_transpose(
    const float* __restrict__ A, float* __restrict__ At)
{
  __shared__ float t[32][33];
  const int tx = threadIdx.x & 31, ty = threadIdx.x >> 5;  // 32x8
  const int x0 = blockIdx.x * 32, y0 = blockIdx.y * 32;
#pragma unroll
  for (int r = 0; r < 32; r += 8)
    t[ty + r][tx] = A[(size_t)(y0 + ty + r) * MM + x0 + tx];
  __syncthreads();
#pragma unroll
  for (int r = 0; r < 32; r += 8)
    At[(size_t)(x0 + ty + r) * MM + y0 + tx] = t[tx][ty + r];
}

// ---------------- sequential top-k gated scan, v3 ----------------
// 8 blocks x 512 threads (8 waves). 2 barriers/step.
// Per-wave SEGMENTED compaction (within-wave prefix only, no cross-wave prefix):
//  - positives: 4 segments (compute wave wv owns rows 64wv..64wv+63), padded to
//    multiples of 32 floats with zeros; counts in pcnt[4].
//  - kept list: 8 segments (gate seg wv = rows 32wv..32wv+31), (idx,val) pairs,
//    padded to multiples of 4 with (0, 0.0); padded counts in kcnt[8].
// Matvec (waves 0-3, thread=row m): su[m] = relu(xp + sum_seg sum_c wT[j][m]*g_j),
// walking the 8 padded segments with wave-uniform scalar trip counts.
// Rank (all 8 waves, row m2 = 32wv + (lane&31), h = lane>>5): strict-rank among
// compacted positives, h-half takes alternating 16-float chunks of each segment
// (counts padded even -> uniform trips), combined via shfl_xor(cnt,32).
__global__ __launch_bounds__(512) void ssma_scan3(
    const float* __restrict__ xproj, const float* __restrict__ state,
    const float* __restrict__ wT, const float* __restrict__ gamma_p,
    const int* __restrict__ topk_p, float* __restrict__ mem_out)
{
  __shared__ __align__(16) float su_all[MM];
  __shared__ __align__(16) float su_pos[4][96];   // padded (mult 32) positives
  __shared__ __align__(16) int   kidx[8][40];     // row idx pre-shifted <<8
  __shared__ __align__(16) float kval[8][40];
  __shared__ __align__(16) int   pcnt[4];         // padded counts (mult 32)
  __shared__ __align__(16) int   kcnt[8];         // padded counts (mult 4)

  const int tid  = threadIdx.x;
  const int wv   = tid >> 6;
  const int lane = tid & 63;
  const int hl   = lane & 31;
  const int h    = lane >> 5;
  const int b    = blockIdx.x;
  const float gamma = *gamma_p;
  const float omg   = 1.0f - gamma;
  const int   rk    = *topk_p - 1;

  const int m  = tid;             // matvec row (waves 0-3 only)
  const int m2 = wv * 32 + hl;    // rank/gate row (all waves, h-duplicated)

  const float* xp  = xproj + (size_t)b * SS * MM;
  const float* wTm = wT + m;

  float mem = state[b * MM + m2];

  // ---- initial k-list from state (general: handles nonzero state) ----
  if (wv < 4){
    float st0 = state[b * MM + m];
    unsigned long long pm0 = __ballot(st0 != 0.0f);
    unsigned int mym = (h == 0) ? (unsigned int)pm0 : (unsigned int)(pm0 >> 32);
    int seg = wv * 2 + h;
    int c   = __popc(mym);
    int pfx = __popc(mym & ((1u << hl) - 1u));
    int cp  = (c + 3) & ~3;
    if (st0 != 0.0f){ kidx[seg][pfx] = m << 8; kval[seg][pfx] = st0; }
    if (hl >= c && hl < cp){ kidx[seg][hl] = 0; kval[seg][hl] = 0.0f; }
    if (hl == 0) kcnt[seg] = cp;
  }
  float xp_cur = (wv < 4) ? xp[m] : 0.0f;
  __syncthreads();

#define MV_SEG(SEG, NCPAD) {                                        \
    int nc_ = (NCPAD) >> 2;                                         \
    const int4*   ip_ = (const int4*)kidx[SEG];                     \
    const float4* vp_ = (const float4*)kval[SEG];                   \
    for (int c_ = 0; c_ < nc_; ++c_){                               \
      int4 ji_ = ip_[c_]; float4 jv_ = vp_[c_];                     \
      s0 = fmaf(wTm[ji_.x], jv_.x, s0);                             \
      s1 = fmaf(wTm[ji_.y], jv_.y, s1);                             \
      s2 = fmaf(wTm[ji_.z], jv_.z, s2);                             \
      s3 = fmaf(wTm[ji_.w], jv_.w, s3); } }

#define RK_SEG(SEG, NUNITS) {                                       \
    int nu_ = (NUNITS);                                             \
    const float4* sp_ = (const float4*)su_pos[SEG];                 \
    for (int u_ = 0; u_ < nu_; ++u_){                               \
      const float4* q_ = sp_ + u_ * 8 + h * 4;                      \
      float4 a_ = q_[0], b_ = q_[1], c_ = q_[2], d_ = q_[3];        \
      cnt += (a_.x > su2) + (a_.y > su2) + (a_.z > su2) + (a_.w > su2) \
           + (b_.x > su2) + (b_.y > su2) + (b_.z > su2) + (b_.w > su2) \
           + (c_.x > su2) + (c_.y > su2) + (c_.z > su2) + (c_.w > su2) \
           + (d_.x > su2) + (d_.y > su2) + (d_.z > su2) + (d_.w > su2); } }

  for (int t = 0; t < SS; ++t){
    float xp_next = 0.0f;
    if (wv < 4){
      int tn = (t + 1 < SS) ? t + 1 : SS - 1;
      xp_next = xp[(size_t)tn * MM + m];

      // ---- sparse matvec over 8 padded segments ----
      int4 kc0 = *(const int4*)&kcnt[0];
      int4 kc1 = *(const int4*)&kcnt[4];
      int n0 = __builtin_amdgcn_readfirstlane(kc0.x);
      int n1 = __builtin_amdgcn_readfirstlane(kc0.y);
      int n2 = __builtin_amdgcn_readfirstlane(kc0.z);
      int n3 = __builtin_amdgcn_readfirstlane(kc0.w);
      int n4 = __builtin_amdgcn_readfirstlane(kc1.x);
      int n5 = __builtin_amdgcn_readfirstlane(kc1.y);
      int n6 = __builtin_amdgcn_readfirstlane(kc1.z);
      int n7 = __builtin_amdgcn_readfirstlane(kc1.w);
      float s0 = 0.f, s1 = 0.f, s2 = 0.f, s3 = 0.f;
      MV_SEG(0, n0) MV_SEG(1, n1) MV_SEG(2, n2) MV_SEG(3, n3)
      MV_SEG(4, n4) MV_SEG(5, n5) MV_SEG(6, n6) MV_SEG(7, n7)
      float s = (s0 + s1) + (s2 + s3);
      float su = fmaxf(s + xp_cur, 0.0f);
      su_all[m] = su;

      // ---- positives compaction into own wave segment ----
      unsigned long long pm = __ballot(su > 0.0f);
      int cw  = __popcll(pm);
      int pfx = __popcll(pm & ((1ull << lane) - 1ull));
      int cp  = (cw + 31) & ~31;
      if (su > 0.0f) su_pos[wv][pfx] = su;
      if (lane >= cw && lane < cp) su_pos[wv][lane] = 0.0f;
      if (lane == 0) pcnt[wv] = cp;
    }
    __syncthreads();   // B1: su_all, su_pos, pcnt ready

    // ---- strict rank among positives ----
    float su2 = su_all[m2];
    int4 pc4 = *(const int4*)pcnt;
    int u0 = __builtin_amdgcn_readfirstlane(pc4.x) >> 5;  // 32-float units
    int u1 = __builtin_amdgcn_readfirstlane(pc4.y) >> 5;
    int u2 = __builtin_amdgcn_readfirstlane(pc4.z) >> 5;
    int u3 = __builtin_amdgcn_readfirstlane(pc4.w) >> 5;
    int cnt = 0;
    RK_SEG(0, u0) RK_SEG(1, u1) RK_SEG(2, u2) RK_SEG(3, u3)
    cnt += __shfl_xor(cnt, 32);

    float g = (su2 > 0.0f && cnt <= rk) ? su2 : 0.0f;
    if (h == 0) mem = fmaf(gamma, mem, omg * g);

    // ---- kept-list compaction into own gate segment ----
    unsigned long long kb = __ballot(h == 0 && g > 0.0f);
    unsigned int km = (unsigned int)kb;
    int ck   = __popc(km);
    int pfx2 = __popc(km & ((1u << hl) - 1u));
    int cp2  = (ck + 3) & ~3;
    if (h == 0){
      if (g > 0.0f){ kidx[wv][pfx2] = m2 << 8; kval[wv][pfx2] = g; }
      if (hl >= ck && hl < cp2){ kidx[wv][hl] = 0; kval[wv][hl] = 0.0f; }
      if (hl == 0) kcnt[wv] = cp2;
    }
    xp_cur = xp_next;
    __syncthreads();   // B2: k-list ready for next matvec
  }
  if (h == 0) mem_out[b * MM + m2] = mem;
#undef MV_SEG
#undef RK_SEG
}

extern "C" void kernel_launch(void* const* d_in, const int* in_sizes, int n_in,
                              void* d_out, int out_size, void* d_ws, size_t ws_size,
                              hipStream_t stream)
{
  const float* x      = (const float*)d_in[0];
  const float* state  = (const float*)d_in[1];
  // d_in[2]=U_w, d_in[3]=V_w unused by the reference
  const float* w1     = (const float*)d_in[4];
  const float* b1     = (const float*)d_in[5];
  const float* w2     = (const float*)d_in[6];
  const float* b2     = (const float*)d_in[7];
  const float* win_w  = (const float*)d_in[8];
  const float* win_b  = (const float*)d_in[9];
  const float* wstate = (const float*)d_in[10];
  const float* gammap = (const float*)d_in[11];
  const int*   topkp  = (const int*)d_in[12];

  float* out  = (float*)d_out;                       // (8,2048,1024)
  float* memo = out + (size_t)BB * SS * DD;          // (8,256)

  char* ws = (char*)d_ws;
  unsigned short* xb   = (unsigned short*)(ws);                   // 32 MB
  unsigned short* w1b  = (unsigned short*)(ws + 33554432);        // 8 MB (reused for wT after gemm1)
  unsigned short* w2b  = (unsigned short*)(ws + 41943040);        // 8 MB
  unsigned short* hbuf = (unsigned short*)(ws + 50331648);        // 128 MB
  float*          xprj = (float*)(ws + 184549376);                // 16 MB
  float*          wT   = (float*)(ws + 33554432);                 // 256 KB, after gemm1

  ssma_pack_bf16<<<16384, 256, 0, stream>>>(x,  xb,  4194304);
  ssma_pack_bf16<<<4096,  256, 0, stream>>>(w1, w1b, 1048576);
  ssma_pack_bf16<<<4096,  256, 0, stream>>>(w2, w2b, 1048576);

  ssma_gemm3_f32<<<dim3(4, 256), 256, 0, stream>>>(x, win_w, win_b, xprj);

  // h = relu(x*w1^T + b1): M=16384, N=4096, K=1024
  ssma_gemm_bt<0><<<dim3(32, 128), 256, 0, stream>>>(xb, w1b, 1024, 4096, b1, nullptr, (void*)hbuf);

  // wT = wstate^T (w1b region is dead after gemm1)
  ssma_transpose<<<dim3(8, 8), 256, 0, stream>>>(wstate, wT);

  // out = x + h*w2^T + b2: M=16384, N=1024, K=4096
  ssma_gemm_bt<1><<<dim3(8, 128), 256, 0, stream>>>(hbuf, w2b, 4096, 1024, b2, x, (void*)out);

  ssma_scan3<<<BB, 512, 0, stream>>>(xprj, state, wT, gammap, topkp, memo);
}

// Round 5
// 5448.243 us; speedup vs baseline: 1.5760x; 1.5760x over previous
//
#include <hip/hip_runtime.h>
#include <stdint.h>

// Problem dims (fixed by setup_inputs)
#define BB 8
#define SS 2048
#define DD 1024
#define HH 4096
#define MM 256

typedef short bf16x8 __attribute__((ext_vector_type(8)));   // 8 bf16 in 4 VGPRs
typedef float f32x4 __attribute__((ext_vector_type(4)));

__device__ inline unsigned short f2bf(float f){
  unsigned u = __builtin_bit_cast(unsigned, f);
  return (unsigned short)((u + 0x7FFFu + ((u >> 16) & 1u)) >> 16);  // RNE
}

// ---------------- pack f32 -> bf16 (4 elems/thread) ----------------
__global__ void ssma_pack_bf16(const float* __restrict__ src,
                               unsigned short* __restrict__ dst, int n4){
  int i = blockIdx.x * blockDim.x + threadIdx.x;
  if (i < n4){
    float4 v = ((const float4*)src)[i];
    ushort4 o;
    o.x = f2bf(v.x); o.y = f2bf(v.y); o.z = f2bf(v.z); o.w = f2bf(v.w);
    ((ushort4*)dst)[i] = o;
  }
}

// ---------------- bf16 MFMA GEMM, C = A * B^T (+epilogue) ----------------
template<int EPI>
__global__ __launch_bounds__(256) void ssma_gemm_bt(
    const unsigned short* __restrict__ A, const unsigned short* __restrict__ Bw,
    int K, int N, const float* __restrict__ bias,
    const float* __restrict__ resid, void* __restrict__ Cout)
{
  __shared__ uint4 As4[512];   // 128x32 bf16 = 8KB
  __shared__ uint4 Bs4[512];
  unsigned short* As = (unsigned short*)As4;
  unsigned short* Bs = (unsigned short*)Bs4;

  const int tid  = threadIdx.x;
  const int lane = tid & 63;
  const int wv   = tid >> 6;
  const int wm   = wv >> 1, wn = wv & 1;      // 2x2 wave grid, 64x64 per wave
  const int m0   = blockIdx.y * 128;
  const int n0   = blockIdx.x * 128;
  const int kq   = lane >> 4;
  const int rl   = lane & 15;

  f32x4 acc[4][4];
#pragma unroll
  for (int a = 0; a < 4; ++a)
#pragma unroll
    for (int b = 0; b < 4; ++b) acc[a][b] = (f32x4){0.f, 0.f, 0.f, 0.f};

  for (int k0 = 0; k0 < K; k0 += 32){
    __syncthreads();
#pragma unroll
    for (int i = 0; i < 2; ++i){
      int c  = tid + 256 * i;
      int r  = c >> 2;
      int c8 = (c & 3) * 8;
      As4[c] = *(const uint4*)(A  + (size_t)(m0 + r) * K + k0 + c8);
      Bs4[c] = *(const uint4*)(Bw + (size_t)(n0 + r) * K + k0 + c8);
    }
    __syncthreads();

    const bf16x8* Ap = (const bf16x8*)As;
    const bf16x8* Bp = (const bf16x8*)Bs;
    bf16x8 af[4], bfr[4];
#pragma unroll
    for (int mi = 0; mi < 4; ++mi) af[mi]  = Ap[(wm * 64 + mi * 16 + rl) * 4 + kq];
#pragma unroll
    for (int ni = 0; ni < 4; ++ni) bfr[ni] = Bp[(wn * 64 + ni * 16 + rl) * 4 + kq];
#pragma unroll
    for (int mi = 0; mi < 4; ++mi)
#pragma unroll
      for (int ni = 0; ni < 4; ++ni)
        acc[mi][ni] = __builtin_amdgcn_mfma_f32_16x16x32_bf16(af[mi], bfr[ni], acc[mi][ni], 0, 0, 0);
  }

#pragma unroll
  for (int mi = 0; mi < 4; ++mi){
#pragma unroll
    for (int ni = 0; ni < 4; ++ni){
      int col = n0 + wn * 64 + ni * 16 + rl;
      float bv = bias[col];
#pragma unroll
      for (int r = 0; r < 4; ++r){
        int row = m0 + wm * 64 + mi * 16 + kq * 4 + r;
        float v = acc[mi][ni][r] + bv;
        if (EPI == 0){
          v = fmaxf(v, 0.0f);
          ((unsigned short*)Cout)[(size_t)row * N + col] = f2bf(v);
        } else {
          v += resid[(size_t)row * N + col];
          ((float*)Cout)[(size_t)row * N + col] = v;
        }
      }
    }
  }
}

// ---------------- exact-f32 GEMM: xproj = x * win_w^T + win_b ----------------
__global__ __launch_bounds__(256) void ssma_gemm3_f32(
    const float* __restrict__ A, const float* __restrict__ Bw,
    const float* __restrict__ bias, float* __restrict__ C)
{
  __shared__ float As[64][17];
  __shared__ float Bs[64][17];
  const int tid = threadIdx.x;
  const int tx = tid & 15, ty = tid >> 4;
  const int m0 = blockIdx.y * 64, n0 = blockIdx.x * 64;
  float acc[4][4];
#pragma unroll
  for (int i = 0; i < 4; ++i)
#pragma unroll
    for (int j = 0; j < 4; ++j) acc[i][j] = 0.f;

  for (int k0 = 0; k0 < DD; k0 += 16){
    __syncthreads();
#pragma unroll
    for (int i = 0; i < 4; ++i){
      int e = tid + 256 * i;
      int r = e >> 4, c = e & 15;
      As[r][c] = A [(size_t)(m0 + r) * DD + k0 + c];
      Bs[r][c] = Bw[(size_t)(n0 + r) * DD + k0 + c];
    }
    __syncthreads();
#pragma unroll
    for (int kk = 0; kk < 16; ++kk){
      float a[4], b[4];
#pragma unroll
      for (int i = 0; i < 4; ++i) a[i] = As[ty * 4 + i][kk];
#pragma unroll
      for (int j = 0; j < 4; ++j) b[j] = Bs[tx * 4 + j][kk];
#pragma unroll
      for (int i = 0; i < 4; ++i)
#pragma unroll
        for (int j = 0; j < 4; ++j) acc[i][j] = fmaf(a[i], b[j], acc[i][j]);
    }
  }
#pragma unroll
  for (int i = 0; i < 4; ++i){
    int row = m0 + ty * 4 + i;
#pragma unroll
    for (int j = 0; j < 4; ++j){
      int col = n0 + tx * 4 + j;
      C[(size_t)row * MM + col] = acc[i][j] + bias[col];
    }
  }
}

// ---------------- 256x256 f32 transpose (wstate -> wT) ----------------
__global__ __launch_bounds__(256) void ssma_transpose(
    const float* __restrict__ A, float* __restrict__ At)
{
  __shared__ float t[32][33];
  const int tx = threadIdx.x & 31, ty = threadIdx.x >> 5;  // 32x8
  const int x0 = blockIdx.x * 32, y0 = blockIdx.y * 32;
#pragma unroll
  for (int r = 0; r < 32; r += 8)
    t[ty + r][tx] = A[(size_t)(y0 + ty + r) * MM + x0 + tx];
  __syncthreads();
#pragma unroll
  for (int r = 0; r < 32; r += 8)
    At[(size_t)(x0 + ty + r) * MM + y0 + tx] = t[tx][ty + r];
}

// ---------------- sequential top-k gated scan, v4 ----------------
// 8 blocks x 1024 threads (16 waves = 4/SIMD for latency hiding).
// Matvec (tid<256, m=tid): su[m] = relu(xp + sum_s wT[j_s*256 + m]*g_s) with
//   COALESCED loads (wave = 64 consecutive m). Kept list zero-padded to >=32
//   slots; first 32 unrolled in two 16-batches, runtime loop only if nkp>32.
// Positives: global ballot+prefix compaction into su_pos (padded to 16-mult).
// Rank: row r=tid>>2, slice q=tid&3; slice sweeps float4s {4i+q}; combine via
//   2x shfl_xor. Strict rank among positives == reference top-k tie rule.
// Kept list: ballot(q==0 && g>0) per wave (16 rows/wave), cross-wave prefix
//   via kmask16. 4 barriers/step.
__global__ __launch_bounds__(1024) void ssma_scan4(
    const float* __restrict__ xproj, const float* __restrict__ state,
    const float* __restrict__ wT, const float* __restrict__ gamma_p,
    const int* __restrict__ topk_p, float* __restrict__ mem_out)
{
  __shared__ __align__(16) float su_all[MM];
  __shared__ __align__(16) float su_pos[MM + 32];
  __shared__ __align__(16) int   kidx[MM + 32];    // j<<8 (float offset of wT row)
  __shared__ __align__(16) float kval[MM + 32];
  __shared__ __align__(16) unsigned long long umask[4];
  __shared__ __align__(16) int   kmask16[16];      // per-wave kept counts

  const int tid  = threadIdx.x;
  const int wv   = tid >> 6;
  const int lane = tid & 63;
  const int b    = blockIdx.x;
  const float gamma = *gamma_p;
  const float omg   = 1.0f - gamma;
  const int   rk    = *topk_p - 1;

  const int r = tid >> 2;         // rank row (all threads)
  const int q = tid & 3;          // rank slice

  const float* xp  = xproj + (size_t)b * SS * MM;
  const float* wTm = wT + tid;    // column base for matvec (tid<256 only)

  float mem = state[b * MM + r];  // q==0 threads own row r

  // ---- initial kept list from state (general: nonzero state handled) ----
  float st0 = 0.0f;
  if (tid < MM){
    st0 = state[b * MM + tid];
    unsigned long long pmi = __ballot(st0 != 0.0f);
    if (lane == 0) umask[wv] = pmi;
  }
  __syncthreads();
  int nkp;
  {
    unsigned long long u0 = umask[0], u1 = umask[1], u2 = umask[2], u3 = umask[3];
    int nk = __popcll(u0) + __popcll(u1) + __popcll(u2) + __popcll(u3);
    if (tid < MM && st0 != 0.0f){
      int before = (wv > 0 ? __popcll(u0) : 0) + (wv > 1 ? __popcll(u1) : 0)
                 + (wv > 2 ? __popcll(u2) : 0);
      unsigned long long mw = (wv == 0 ? u0 : wv == 1 ? u1 : wv == 2 ? u2 : u3);
      int pos = before + __popcll(mw & ((1ull << lane) - 1ull));
      kidx[pos] = tid << 8;
      kval[pos] = st0;
    }
    nkp = (nk + 15) & ~15; if (nkp < 32) nkp = 32;
    if (tid >= MM && tid < MM + 64){
      int t2 = tid - MM;
      if (nk + t2 < nkp){ kidx[nk + t2] = 0; kval[nk + t2] = 0.0f; }
    }
  }
  float xp_cur = (tid < MM) ? xp[tid] : 0.0f;
  __syncthreads();

  for (int t = 0; t < SS; ++t){
    // ================= matvec (waves 0-3) =================
    float su = 0.0f;
    float xp_next = 0.0f;
    if (tid < MM){
      int tn = (t + 1 < SS) ? t + 1 : SS - 1;
      xp_next = xp[(size_t)tn * MM + tid];      // prefetch: independent load

      const int4*   ip = (const int4*)kidx;
      const float4* vp = (const float4*)kval;
      float a0=0.f,a1=0.f,a2=0.f,a3=0.f,a4=0.f,a5=0.f,a6=0.f,a7=0.f;
      // batch A: slots 0..15
      {
        int4 I0=ip[0], I1=ip[1], I2=ip[2], I3=ip[3];
        float4 V0=vp[0], V1=vp[1], V2=vp[2], V3=vp[3];
        float w00=wTm[I0.x], w01=wTm[I0.y], w02=wTm[I0.z], w03=wTm[I0.w];
        float w10=wTm[I1.x], w11=wTm[I1.y], w12=wTm[I1.z], w13=wTm[I1.w];
        float w20=wTm[I2.x], w21=wTm[I2.y], w22=wTm[I2.z], w23=wTm[I2.w];
        float w30=wTm[I3.x], w31=wTm[I3.y], w32=wTm[I3.z], w33=wTm[I3.w];
        a0=fmaf(w00,V0.x,a0); a1=fmaf(w01,V0.y,a1); a2=fmaf(w02,V0.z,a2); a3=fmaf(w03,V0.w,a3);
        a4=fmaf(w10,V1.x,a4); a5=fmaf(w11,V1.y,a5); a6=fmaf(w12,V1.z,a6); a7=fmaf(w13,V1.w,a7);
        a0=fmaf(w20,V2.x,a0); a1=fmaf(w21,V2.y,a1); a2=fmaf(w22,V2.z,a2); a3=fmaf(w23,V2.w,a3);
        a4=fmaf(w30,V3.x,a4); a5=fmaf(w31,V3.y,a5); a6=fmaf(w32,V3.z,a6); a7=fmaf(w33,V3.w,a7);
      }
      // batch B: slots 16..31
      {
        int4 I0=ip[4], I1=ip[5], I2=ip[6], I3=ip[7];
        float4 V0=vp[4], V1=vp[5], V2=vp[6], V3=vp[7];
        float w00=wTm[I0.x], w01=wTm[I0.y], w02=wTm[I0.z], w03=wTm[I0.w];
        float w10=wTm[I1.x], w11=wTm[I1.y], w12=wTm[I1.z], w13=wTm[I1.w];
        float w20=wTm[I2.x], w21=wTm[I2.y], w22=wTm[I2.z], w23=wTm[I2.w];
        float w30=wTm[I3.x], w31=wTm[I3.y], w32=wTm[I3.z], w33=wTm[I3.w];
        a0=fmaf(w00,V0.x,a0); a1=fmaf(w01,V0.y,a1); a2=fmaf(w02,V0.z,a2); a3=fmaf(w03,V0.w,a3);
        a4=fmaf(w10,V1.x,a4); a5=fmaf(w11,V1.y,a5); a6=fmaf(w12,V1.z,a6); a7=fmaf(w13,V1.w,a7);
        a0=fmaf(w20,V2.x,a0); a1=fmaf(w21,V2.y,a1); a2=fmaf(w22,V2.z,a2); a3=fmaf(w23,V2.w,a3);
        a4=fmaf(w30,V3.x,a4); a5=fmaf(w31,V3.y,a5); a6=fmaf(w32,V3.z,a6); a7=fmaf(w33,V3.w,a7);
      }
      // rare overflow (ties pushed kept count past 32)
      if (nkp > 32){
        for (int c4 = 8; c4 < (nkp >> 2); ++c4){
          int4 I = ip[c4]; float4 V = vp[c4];
          a0 = fmaf(wTm[I.x], V.x, a0); a1 = fmaf(wTm[I.y], V.y, a1);
          a2 = fmaf(wTm[I.z], V.z, a2); a3 = fmaf(wTm[I.w], V.w, a3);
        }
      }
      float s = ((a0 + a1) + (a2 + a3)) + ((a4 + a5) + (a6 + a7));
      su = fmaxf(s + xp_cur, 0.0f);
      su_all[tid] = su;
      unsigned long long pm = __ballot(su > 0.0f);
      if (lane == 0) umask[wv] = pm;
    }
    __syncthreads();   // B1: su_all + umask ready

    // ================= positives compaction =================
    int Ppad;
    {
      unsigned long long u0 = umask[0], u1 = umask[1], u2 = umask[2], u3 = umask[3];
      int P = __popcll(u0) + __popcll(u1) + __popcll(u2) + __popcll(u3);
      Ppad = (P + 15) & ~15;
      if (tid < MM && su > 0.0f){
        int before = (wv > 0 ? __popcll(u0) : 0) + (wv > 1 ? __popcll(u1) : 0)
                   + (wv > 2 ? __popcll(u2) : 0);
        unsigned long long mw = (wv == 0 ? u0 : wv == 1 ? u1 : wv == 2 ? u2 : u3);
        int pos = before + __popcll(mw & ((1ull << lane) - 1ull));
        su_pos[pos] = su;
      }
      if (tid >= MM && tid < MM + 32){
        int t2 = tid - MM;
        if (P + t2 < Ppad) su_pos[P + t2] = 0.0f;
      }
    }
    __syncthreads();   // B2: su_pos ready

    // ================= strict rank (4 slices per row) =================
    float su2 = su_all[r];
    int trips = Ppad >> 4;               // uniform float4-quads per slice
    int cnt = 0;
    const float4* spp = (const float4*)su_pos;
    for (int i = 0; i < trips; ++i){
      float4 v = spp[i * 4 + q];
      cnt += (v.x > su2) + (v.y > su2) + (v.z > su2) + (v.w > su2);
    }
    cnt += __shfl_xor(cnt, 1);
    cnt += __shfl_xor(cnt, 2);

    float g = (su2 > 0.0f && cnt <= rk) ? su2 : 0.0f;
    if (q == 0) mem = fmaf(gamma, mem, omg * g);

    unsigned long long kb = __ballot(q == 0 && g > 0.0f);
    unsigned long long kbS = kb & 0x1111111111111111ull;
    if (lane == 0) kmask16[wv] = __popcll(kbS);
    __syncthreads();   // B3: kmask16 ready

    // ================= kept-list write =================
    {
      int4 k0 = *(const int4*)&kmask16[0];
      int4 k1 = *(const int4*)&kmask16[4];
      int4 k2 = *(const int4*)&kmask16[8];
      int4 k3 = *(const int4*)&kmask16[12];
      int cw[16] = {k0.x,k0.y,k0.z,k0.w, k1.x,k1.y,k1.z,k1.w,
                    k2.x,k2.y,k2.z,k2.w, k3.x,k3.y,k3.z,k3.w};
      int nk = 0, before = 0;
#pragma unroll
      for (int w = 0; w < 16; ++w){
        nk += cw[w];
        if (w < wv) before += cw[w];
      }
      if (q == 0 && g > 0.0f){
        int pos = before + __popcll(kbS & ((1ull << lane) - 1ull));
        kidx[pos] = r << 8;
        kval[pos] = g;
      }
      nkp = (nk + 15) & ~15; if (nkp < 32) nkp = 32;
      if (tid < 64){
        if (nk + tid < nkp){ kidx[nk + tid] = 0; kval[nk + tid] = 0.0f; }
      }
    }
    xp_cur = xp_next;
    __syncthreads();   // B4: kept list ready for next matvec
  }
  if (q == 0) mem_out[b * MM + r] = mem;
}

extern "C" void kernel_launch(void* const* d_in, const int* in_sizes, int n_in,
                              void* d_out, int out_size, void* d_ws, size_t ws_size,
                              hipStream_t stream)
{
  const float* x      = (const float*)d_in[0];
  const float* state  = (const float*)d_in[1];
  // d_in[2]=U_w, d_in[3]=V_w unused by the reference
  const float* w1     = (const float*)d_in[4];
  const float* b1     = (const float*)d_in[5];
  const float* w2     = (const float*)d_in[6];
  const float* b2     = (const float*)d_in[7];
  const float* win_w  = (const float*)d_in[8];
  const float* win_b  = (const float*)d_in[9];
  const float* wstate = (const float*)d_in[10];
  const float* gammap = (const float*)d_in[11];
  const int*   topkp  = (const int*)d_in[12];

  float* out  = (float*)d_out;                       // (8,2048,1024)
  float* memo = out + (size_t)BB * SS * DD;          // (8,256)

  char* ws = (char*)d_ws;
  unsigned short* xb   = (unsigned short*)(ws);                   // 32 MB
  unsigned short* w1b  = (unsigned short*)(ws + 33554432);        // 8 MB (reused for wT after gemm1)
  unsigned short* w2b  = (unsigned short*)(ws + 41943040);        // 8 MB
  unsigned short* hbuf = (unsigned short*)(ws + 50331648);        // 128 MB
  float*          xprj = (float*)(ws + 184549376);                // 16 MB
  float*          wT   = (float*)(ws + 33554432);                 // 256 KB, after gemm1

  ssma_pack_bf16<<<16384, 256, 0, stream>>>(x,  xb,  4194304);
  ssma_pack_bf16<<<4096,  256, 0, stream>>>(w1, w1b, 1048576);
  ssma_pack_bf16<<<4096,  256, 0, stream>>>(w2, w2b, 1048576);

  ssma_gemm3_f32<<<dim3(4, 256), 256, 0, stream>>>(x, win_w, win_b, xprj);

  // h = relu(x*w1^T + b1): M=16384, N=4096, K=1024
  ssma_gemm_bt<0><<<dim3(32, 128), 256, 0, stream>>>(xb, w1b, 1024, 4096, b1, nullptr, (void*)hbuf);

  // wT = wstate^T (w1b region is dead after gemm1)
  ssma_transpose<<<dim3(8, 8), 256, 0, stream>>>(wstate, wT);

  // out = x + h*w2^T + b2: M=16384, N=1024, K=4096
  ssma_gemm_bt<1><<<dim3(8, 128), 256, 0, stream>>>(hbuf, w2b, 4096, 1024, b2, x, (void*)out);

  ssma_scan4<<<BB, 1024, 0, stream>>>(xprj, state, wT, gammap, topkp, memo);
}